// Round 9
// baseline (1016.055 us; speedup 1.0000x reference)
//
#include <hip/hip_runtime.h>
#include <hip/hip_cooperative_groups.h>
#include <hip/hip_bf16.h>
#include <cstdint>

namespace cg = cooperative_groups;

#define NNODES 20000
#define NEDGES 640000
#define ETOT   (NEDGES + NNODES)
#define NGROUP 64
#define HC     256
#define DOUT   32
#define EBLK   5120                     // edges per CSR-build slice (divides NEDGES)
#define NBLK   (NEDGES / EBLK)          // 125
#define CBLK   ((NNODES + 255) / 256)   // 79
#define GBLK   (NNODES / 16)            // 1250 gemm tiles
#define GPITCH 1280
#define MB     768                      // mega grid (3 blocks/CU guaranteed: 3*40KB=120KB<160KB)
#define HALFN  10240                    // hist/scatter pass width (40 KB LDS ints)
#define SMEMB  (HALFN * 4)

typedef short bf16x8 __attribute__((ext_vector_type(8)));
typedef short s16x4  __attribute__((ext_vector_type(4)));
typedef float f32x4  __attribute__((ext_vector_type(4)));
typedef float f32x2  __attribute__((ext_vector_type(2)));
typedef int   s32x4  __attribute__((ext_vector_type(4)));
typedef unsigned int u32x4 __attribute__((ext_vector_type(4)));

__device__ __forceinline__ float bs2f(short v) {
    union { unsigned int u; float f; } c; c.u = ((unsigned int)(unsigned short)v) << 16; return c.f;
}
__device__ __forceinline__ short f2bs(float v) {
    __hip_bfloat16 b = __float2bfloat16(v);
    union { __hip_bfloat16 b; short s; } u; u.b = b; return u.s;
}
__device__ __forceinline__ float ldf(const void* __restrict__ p, size_t i, int bf) {
    return bf ? __bfloat162float(((const __hip_bfloat16*)p)[i]) : ((const float*)p)[i];
}
__device__ __forceinline__ int ld_idx(const int* __restrict__ p, size_t i, int f64) {
    return f64 ? p[2 * i] : p[i];
}
// local flag probes (cheap; every block computes identical values -> no flag buffer)
__device__ __forceinline__ int probe_edge64(const int* __restrict__ ei) {
    int l = threadIdx.x & 63;
    int zeros = 0;
#pragma unroll
    for (int r = 0; r < 4; r++)
        zeros += __popcll(__ballot(ei[2 * (r * 64 + l) + 1] == 0));
    return (zeros > 200) ? 1 : 0;
}
__device__ __forceinline__ int probe_xbf(const unsigned int* __restrict__ xw) {
    int l = threadIdx.x & 63;
    int ones = 0;
#pragma unroll
    for (int r = 0; r < 4; r++)
        ones += __popcll(__ballot((xw[r * 64 + l] >> 14) & 1));
    return (ones < 64) ? 1 : 0;
}

// ================= device phase bodies (shared by mega + fallback) =================

// 2-pass LDS histogram of slice b (self-loops excluded; handled by base).
__device__ __forceinline__ void dev_hist(int b, int f, const int* __restrict__ ei,
                                         int* __restrict__ H, int* hl) {
    int t = threadIdx.x;
    for (int pass = 0; pass < 2; ++pass) {
        int nbase = pass * HALFN;
        int span = NNODES - nbase; if (span > HALFN) span = HALFN;
        s32x4* h4 = reinterpret_cast<s32x4*>(hl);
        for (int i = t; i < HALFN / 4; i += 256) h4[i] = (s32x4){0, 0, 0, 0};
        __syncthreads();
        int s0 = b * EBLK;
        if (f) {
            const int* d64 = ei + 2 * NEDGES;
            for (int i0 = s0; i0 < s0 + EBLK; i0 += 512) {
                int i = i0 + 2 * t;
                s32x4 v = *reinterpret_cast<const s32x4*>(d64 + 2 * (size_t)i);
                unsigned d0 = (unsigned)(v[0] - nbase), d1 = (unsigned)(v[2] - nbase);
                if (d0 < (unsigned)span) atomicAdd(&hl[d0], 1);
                if (d1 < (unsigned)span) atomicAdd(&hl[d1], 1);
            }
        } else {
            const int* d32 = ei + NEDGES;
            for (int i0 = s0; i0 < s0 + EBLK; i0 += 1024) {
                int i = i0 + 4 * t;
                s32x4 v = *reinterpret_cast<const s32x4*>(d32 + i);
#pragma unroll
                for (int k = 0; k < 4; k++) {
                    unsigned d = (unsigned)(v[k] - nbase);
                    if (d < (unsigned)span) atomicAdd(&hl[d], 1);
                }
            }
        }
        __syncthreads();
        int* Hb = H + (size_t)b * NNODES + nbase;
        for (int i = t; i < span; i += 256) Hb[i] = hl[i];
        if (pass == 0) __syncthreads();
    }
}

__device__ __forceinline__ void dev_wt(int u, int bf,
                                       const void* __restrict__ W1, const void* __restrict__ W2,
                                       __hip_bfloat16* __restrict__ Wt1, __hip_bfloat16* __restrict__ Wt2) {
    int i = u * 256 + threadIdx.x;
    int which = i >> 16;
    int j = i & 65535;
    int k = j >> 8, n = j & 255;
    const void* W = which ? W2 : W1;
    __hip_bfloat16* Wt = which ? Wt2 : Wt1;
    Wt[(size_t)n * 256 + k] = __float2bfloat16(ldf(W, (size_t)k * 256 + n, bf));
}

__device__ __forceinline__ void dev_colsum(int blk, const int* __restrict__ H,
                                           int* __restrict__ deg, int* __restrict__ bsum,
                                           int* wred) {
    int t = threadIdx.x, n = blk * 256 + t;
    int s = 0;
    if (n < NNODES) {
#pragma unroll 5
        for (int b = 0; b < NBLK; b++) s += H[(size_t)b * NNODES + n];
        s += 1;  // self-loop
        deg[n] = s;
    }
    int r = s;
#pragma unroll
    for (int o = 1; o < 64; o <<= 1) r += __shfl_xor(r, o);
    if ((t & 63) == 0) wred[t >> 6] = r;
    __syncthreads();
    if (t == 0) bsum[blk] = wred[0] + wred[1] + wred[2] + wred[3];
}

__device__ __forceinline__ void dev_base(int blk, int* __restrict__ H,
                                         const int* __restrict__ deg, const int* __restrict__ bsum,
                                         int* __restrict__ off, int* __restrict__ csr,
                                         int* scr /*5 ints*/) {
    int t = threadIdx.x;
    int n = blk * 256 + t;
    int d = (n < NNODES) ? deg[n] : 0;
    int lane = t & 63, w = t >> 6;
    int sc = d;
#pragma unroll
    for (int o = 1; o < 64; o <<= 1) {
        int u = __shfl_up(sc, o);
        if (lane >= o) sc += u;
    }
    if (lane == 63) scr[w] = sc;
    if (w == 0) {  // exclusive prefix of block sums (CBLK=79)
        int v = (lane < blk) ? bsum[lane] : 0;
        if (lane + 64 < blk) v += bsum[lane + 64];
#pragma unroll
        for (int o = 1; o < 64; o <<= 1) v += __shfl_xor(v, o);
        if (lane == 0) scr[4] = v;
    }
    __syncthreads();
    int woff = 0;
    for (int i = 0; i < w; i++) woff += scr[i];
    int excl = woff + sc - d;
    if (blk == 0 && t == 0) off[NNODES] = ETOT;
    if (n < NNODES) {
        int o0 = scr[4] + excl;
        off[n] = o0;
        csr[o0] = n;          // self-loop first
        int run = o0 + 1;
#pragma unroll 5
        for (int b = 0; b < NBLK; b++) {
            size_t idx = (size_t)b * NNODES + n;
            int tt = H[idx];
            H[idx] = run;
            run += tt;
        }
    }
}

__device__ __forceinline__ void dev_scatter(int b, int f, const int* __restrict__ ei,
                                            const int* __restrict__ H, int* __restrict__ csr,
                                            int* hl) {
    int t = threadIdx.x;
    for (int pass = 0; pass < 2; ++pass) {
        int nbase = pass * HALFN;
        int span = NNODES - nbase; if (span > HALFN) span = HALFN;
        const int* Hb = H + (size_t)b * NNODES + nbase;
        for (int i = t; i < span; i += 256) hl[i] = Hb[i];
        __syncthreads();
        int s0 = b * EBLK;
        if (f) {
            const int* d64 = ei + 2 * NEDGES;
            for (int i0 = s0; i0 < s0 + EBLK; i0 += 512) {
                int i = i0 + 2 * t;
                s32x4 sv = *reinterpret_cast<const s32x4*>(ei + 2 * (size_t)i);
                s32x4 dv = *reinterpret_cast<const s32x4*>(d64 + 2 * (size_t)i);
                unsigned d0 = (unsigned)(dv[0] - nbase), d1 = (unsigned)(dv[2] - nbase);
                if (d0 < (unsigned)span) { int p = atomicAdd(&hl[d0], 1); csr[p] = sv[0]; }
                if (d1 < (unsigned)span) { int p = atomicAdd(&hl[d1], 1); csr[p] = sv[2]; }
            }
        } else {
            const int* d32 = ei + NEDGES;
            for (int i0 = s0; i0 < s0 + EBLK; i0 += 1024) {
                int i = i0 + 4 * t;
                s32x4 sv = *reinterpret_cast<const s32x4*>(ei + i);
                s32x4 dv = *reinterpret_cast<const s32x4*>(d32 + i);
#pragma unroll
                for (int k = 0; k < 4; k++) {
                    unsigned d = (unsigned)(dv[k] - nbase);
                    if (d < (unsigned)span) { int p = atomicAdd(&hl[d], 1); csr[p] = sv[k]; }
                }
            }
        }
        if (pass == 0) __syncthreads();
    }
}

// one 16-row GEMM tile (4 waves; wave w = head w's 64 cols); fused es/ed + block gmax
__device__ __forceinline__ void dev_gemm(int tile, const void* __restrict__ A,
                                         const __hip_bfloat16* __restrict__ Bt,
                                         __hip_bfloat16* __restrict__ Hout,
                                         const void* __restrict__ a_src, const void* __restrict__ a_dst,
                                         float* __restrict__ es4, float* __restrict__ ed4,
                                         float* __restrict__ gpart, int bf, int abf,
                                         u32x4* hst4) {
    int w    = threadIdx.x >> 6;
    int lane = threadIdx.x & 63;
    int mr   = lane & 15;
    int quad = lane >> 4;
    int r0   = tile * 16;
    f32x4 acc[4];
#pragma unroll
    for (int j = 0; j < 4; j++) acc[j] = (f32x4){0.f, 0.f, 0.f, 0.f};
    size_t rowoff = (size_t)(r0 + mr) * HC;
    const __hip_bfloat16* Btw = Bt + (size_t)w * 64 * HC;
    for (int kk = 0; kk < HC; kk += 32) {
        bf16x8 a;
        if (abf) {
            a = *reinterpret_cast<const bf16x8*>((const __hip_bfloat16*)A + rowoff + kk + quad * 8);
        } else {
            const float* af = (const float*)A + rowoff + kk + quad * 8;
            f32x4 lo = *reinterpret_cast<const f32x4*>(af);
            f32x4 hi = *reinterpret_cast<const f32x4*>(af + 4);
#pragma unroll
            for (int ii = 0; ii < 4; ii++) { a[ii] = f2bs(lo[ii]); a[ii + 4] = f2bs(hi[ii]); }
        }
#pragma unroll
        for (int j = 0; j < 4; j++) {
            bf16x8 b = *reinterpret_cast<const bf16x8*>(Btw + (size_t)(j * 16 + mr) * HC + kk + quad * 8);
            acc[j] = __builtin_amdgcn_mfma_f32_16x16x32_bf16(a, b, acc[j], 0, 0, 0);
        }
    }
    short* hst = reinterpret_cast<short*>(hst4);
#pragma unroll
    for (int j = 0; j < 4; j++)
#pragma unroll
        for (int r = 0; r < 4; r++)
            hst[(quad * 4 + r) * HC + w * 64 + j * 16 + mr] = f2bs(acc[j][r]);
    float ps[4] = {0.f, 0.f, 0.f, 0.f}, pd[4] = {0.f, 0.f, 0.f, 0.f};
#pragma unroll
    for (int j = 0; j < 4; j++) {
        float asv = ldf(a_src, (size_t)(w * 64 + j * 16 + mr), bf);
        float adv = ldf(a_dst, (size_t)(w * 64 + j * 16 + mr), bf);
#pragma unroll
        for (int r = 0; r < 4; r++) {
            ps[r] = fmaf(acc[j][r], asv, ps[r]);
            pd[r] = fmaf(acc[j][r], adv, pd[r]);
        }
    }
#pragma unroll
    for (int o = 1; o < 16; o <<= 1)
#pragma unroll
        for (int r = 0; r < 4; r++) {
            ps[r] += __shfl_xor(ps[r], o);
            pd[r] += __shfl_xor(pd[r], o);
        }
    float pm = fmaxf(fmaxf(ps[0], ps[1]), fmaxf(ps[2], ps[3]));
    pm = fmaxf(pm, __shfl_xor(pm, 16));
    pm = fmaxf(pm, __shfl_xor(pm, 32));
    if (lane == 0) gpart[w * GPITCH + tile] = pm;
    if (mr == 0)
#pragma unroll
        for (int r = 0; r < 4; r++) {
            int row = r0 + quad * 4 + r;
            es4[(size_t)row * 4 + w] = ps[r];
            ed4[(size_t)row * 4 + w] = pd[r];
        }
    __syncthreads();
    u32x4* dst = reinterpret_cast<u32x4*>((short*)Hout + (size_t)r0 * HC);
    dst[threadIdx.x]       = hst4[threadIdx.x];
    dst[threadIdx.x + 256] = hst4[threadIdx.x + 256];
    __syncthreads();  // protect hst4 reuse by next tile
}

// bound-max softmax + gather aggregation over nodes n0, n0+nstr, ...
// smem carve: p_lds 1024 floats | s_lds 256 ints | gm 4 floats
__device__ __forceinline__ void dev_agg(int n0, int nstr,
                                        const __hip_bfloat16* __restrict__ Hb,
                                        const float* __restrict__ es4, const float* __restrict__ ed4,
                                        const void* __restrict__ bias,
                                        const int* __restrict__ off, const int* __restrict__ csr,
                                        const float* __restrict__ gpart, int bf,
                                        __hip_bfloat16* __restrict__ out, int* smem) {
    float (*p_lds)[64] = reinterpret_cast<float(*)[64]>(smem);       // [4 heads][64] per wave slot
    int wv = threadIdx.x >> 6;
    int l  = threadIdx.x & 63;
    int half = l >> 5;
    int hl   = l & 31;
    int hd8  = hl >> 3;
    float* pw = (float*)(smem) + wv * 256;        // this wave's 4x64 weights
    int*   sw = smem + 1024 + wv * 64;            // this wave's 64 indices
    float* gm_s = (float*)(smem + 1280);
    {   // per-block gmax re-reduce (wave wv = head wv), 2-way MLP
        const float* gp = gpart + wv * GPITCH;
        float ma = -INFINITY, mb = -INFINITY;
        int i = l;
        for (; i + 64 < GBLK; i += 128) { ma = fmaxf(ma, gp[i]); mb = fmaxf(mb, gp[i + 64]); }
        if (i < GBLK) ma = fmaxf(ma, gp[i]);
        float m = fmaxf(ma, mb);
#pragma unroll
        for (int o = 32; o; o >>= 1) m = fmaxf(m, __shfl_xor(m, o));
        if (l == 0) gm_s[wv] = m;
    }
    __syncthreads();
    f32x4 gm = (f32x4){gm_s[0], gm_s[1], gm_s[2], gm_s[3]};
    for (int n = n0; n < NNODES; n += nstr) {
        int base = off[n], deg = off[n + 1] - base;
        f32x4 edv = *reinterpret_cast<const f32x4*>(ed4 + (size_t)n * 4);
        f32x4 M;
#pragma unroll
        for (int h = 0; h < 4; h++) {
            float t0 = gm[h] + edv[h];
            M[h] = (t0 > 0.f) ? t0 : 0.2f * t0;
        }
        f32x4 dsum = (f32x4){0.f, 0.f, 0.f, 0.f};
        f32x2 acc2[4];
#pragma unroll
        for (int d = 0; d < 4; d++) acc2[d] = (f32x2){0.f, 0.f};
        for (int c0 = 0; c0 < deg; c0 += 64) {
            int cn = min(deg - c0, 64);
            int s = 0;
            f32x4 pv = (f32x4){0.f, 0.f, 0.f, 0.f};
            if (l < cn) {
                s = csr[base + c0 + l];
                f32x4 e = *reinterpret_cast<const f32x4*>(es4 + (size_t)s * 4);
#pragma unroll
                for (int h = 0; h < 4; h++) {
                    float t = e[h] + edv[h];
                    t = (t > 0.f) ? t : 0.2f * t;
                    pv[h] = __expf(t - M[h]);
                }
            }
            sw[l] = s;
#pragma unroll
            for (int h = 0; h < 4; h++) pw[h * 64 + l] = pv[h];
#pragma unroll
            for (int h = 0; h < 4; h++) dsum[h] += pv[h];
            int jn = (cn + 15) & ~15;
            for (int j = 0; j < jn; j += 16) {
                int e0 = j + 8 * half;
                s32x4 sA = *reinterpret_cast<const s32x4*>(&sw[e0]);
                s32x4 sB = *reinterpret_cast<const s32x4*>(&sw[e0 + 4]);
                f32x4 pA = *reinterpret_cast<const f32x4*>(&pw[hd8 * 64 + e0]);
                f32x4 pB = *reinterpret_cast<const f32x4*>(&pw[hd8 * 64 + e0 + 4]);
                u32x4 hv[8];
#pragma unroll
                for (int i = 0; i < 8; i++) {
                    int sj = (i < 4) ? sA[i & 3] : sB[i & 3];
                    hv[i] = *reinterpret_cast<const u32x4*>(Hb + (size_t)sj * HC + hl * 8);
                }
#pragma unroll
                for (int i = 0; i < 8; i++) {
                    float p = (i < 4) ? pA[i & 3] : pB[i & 3];
#pragma unroll
                    for (int d = 0; d < 4; d++) {
                        unsigned int u = hv[i][d];
                        f32x2 h2;
                        h2.x = __uint_as_float(u << 16);
                        h2.y = __uint_as_float(u & 0xFFFF0000u);
                        acc2[d] += h2 * p;
                    }
                }
            }
        }
#pragma unroll
        for (int o = 32; o; o >>= 1)
#pragma unroll
            for (int h = 0; h < 4; h++) dsum[h] += __shfl_xor(dsum[h], o);
#pragma unroll
        for (int d = 0; d < 4; d++) {
            acc2[d].x += __shfl_xor(acc2[d].x, 32);
            acc2[d].y += __shfl_xor(acc2[d].y, 32);
        }
        float rinv = 1.0f / fmaxf(dsum[hd8], 1e-16f);
        if (half == 0) {
            bf16x8 ov;
#pragma unroll
            for (int d = 0; d < 4; d++) {
                float v0 = acc2[d].x * rinv + ldf(bias, (size_t)hl * 8 + 2 * d, bf);
                float v1 = acc2[d].y * rinv + ldf(bias, (size_t)hl * 8 + 2 * d + 1, bf);
                ov[2 * d]     = f2bs(fmaxf(v0, 0.f));
                ov[2 * d + 1] = f2bs(fmaxf(v1, 0.f));
            }
            *reinterpret_cast<bf16x8*>(out + (size_t)n * HC + hl * 8) = ov;
        }
    }
    (void)p_lds;
}

__device__ __forceinline__ void dev_groupsum(int b, int f, const __hip_bfloat16* __restrict__ X2,
                                             const int* __restrict__ batch,
                                             float* __restrict__ sx, int* __restrict__ cnt) {
    const int RPB = NNODES / 250;  // 80
    int sub = threadIdx.x >> 6, l = threadIdx.x & 63;
    int r = b * RPB + sub;
    f32x4 acc = (f32x4){0.f, 0.f, 0.f, 0.f};
    int curg = ld_idx(batch, r, f);
    int cacc = 0;
    for (int k = 0; k < RPB / 4; k++, r += 4) {
        int g = ld_idx(batch, r, f);
        if (g != curg) {
#pragma unroll
            for (int c = 0; c < 4; c++) atomicAdd(&sx[(size_t)curg * HC + l * 4 + c], acc[c]);
            if (l == 0) atomicAdd(&cnt[curg], cacc);
            acc = (f32x4){0.f, 0.f, 0.f, 0.f}; cacc = 0; curg = g;
        }
        s16x4 hv = *reinterpret_cast<const s16x4*>(X2 + (size_t)r * HC + l * 4);
#pragma unroll
        for (int c = 0; c < 4; c++) acc[c] += bs2f(hv[c]);
        cacc++;
    }
#pragma unroll
    for (int c = 0; c < 4; c++) atomicAdd(&sx[(size_t)curg * HC + l * 4 + c], acc[c]);
    if (l == 0) atomicAdd(&cnt[curg], cacc);
}

__device__ __forceinline__ void dev_final(int g, int bf, const float* __restrict__ sx,
                                          const void* __restrict__ Wp, const void* __restrict__ bp,
                                          const int* __restrict__ cnt, void* __restrict__ out,
                                          float* red /*256 floats*/) {
    int t = threadIdx.x;
    int c = t & 31, seg = t >> 5;
    const float* sxg = sx + (size_t)g * HC;
    float a = 0.f;
#pragma unroll
    for (int k = 0; k < 32; k++) {
        int kk = seg * 32 + k;
        a = fmaf(sxg[kk], ldf(Wp, (size_t)kk * DOUT + c, bf), a);
    }
    red[seg * 32 + c] = a;
    __syncthreads();
    if (t < 32) {
        float s = 0.f;
#pragma unroll
        for (int i = 0; i < 8; i++) s += red[i * 32 + t];
        int ct = cnt[g];
        float v = (ct > 0) ? (s / ct + ldf(bp, (size_t)t, bf)) : 0.f;
        if (bf) ((__hip_bfloat16*)out)[g * DOUT + t] = __float2bfloat16(v);
        else    ((float*)out)[g * DOUT + t]          = v;
    }
}

// ================= cooperative mega-kernel =================
__global__ void k_mega(const void* x, const int* ei, const int* bat,
                       const void* W1, const void* as1, const void* ad1, const void* b1,
                       const void* W2, const void* as2, const void* ad2, const void* b2,
                       const void* Wp, const void* bp,
                       __hip_bfloat16* hb, __hip_bfloat16* xb, __hip_bfloat16* xb2,
                       __hip_bfloat16* Wt1, __hip_bfloat16* Wt2,
                       float* es, float* ed, int* H, int* deg, int* off, int* csr,
                       int* bsum, float* gpart, float* sx, int* cnt, void* out) {
    extern __shared__ int smem[];  // SMEMB bytes
    cg::grid_group grid = cg::this_grid();
    int bid = blockIdx.x, t = threadIdx.x;
    int f  = probe_edge64(ei);
    int bf = probe_xbf((const unsigned int*)x);

    // P0: hist slices (bid<NBLK) | weight transposes + readout zero (else)
    if (bid < NBLK) {
        dev_hist(bid, f, ei, H, smem);
    } else {
        for (int u = bid - NBLK; u < 512; u += MB - NBLK)
            dev_wt(u, bf, W1, W2, Wt1, Wt2);
        if (bid == NBLK) {
            for (int q = t; q < NGROUP * HC; q += 256) sx[q] = 0.f;
            if (t < NGROUP) cnt[t] = 0;
        }
    }
    grid.sync();
    // P1: colsum
    if (bid < CBLK) dev_colsum(bid, H, deg, bsum, smem);
    grid.sync();
    // P2: base (+ self-loop csr entries)
    if (bid < CBLK) dev_base(bid, H, deg, bsum, off, csr, smem);
    grid.sync();
    // P3: scatter (bid<NBLK) || gemm layer-1 (else)
    if (bid < NBLK) {
        dev_scatter(bid, f, ei, H, csr, smem);
    } else {
        for (int tile = bid - NBLK; tile < GBLK; tile += MB - NBLK)
            dev_gemm(tile, x, Wt1, hb, as1, ad1, es, ed, gpart, bf, bf, (u32x4*)smem);
    }
    grid.sync();
    // P4: agg layer-1
    dev_agg(bid * 4 + (t >> 6), MB * 4, hb, es, ed, b1, off, csr, gpart, bf, xb, smem);
    grid.sync();
    // P5: gemm layer-2 (bf16 input)
    for (int tile = bid; tile < GBLK; tile += MB)
        dev_gemm(tile, xb, Wt2, hb, as2, ad2, es, ed, gpart, bf, 1, (u32x4*)smem);
    grid.sync();
    // P6: agg layer-2
    dev_agg(bid * 4 + (t >> 6), MB * 4, hb, es, ed, b2, off, csr, gpart, bf, xb2, smem);
    grid.sync();
    // P7: groupsum
    if (bid < 250) dev_groupsum(bid, f, xb2, bat, sx, cnt);
    grid.sync();
    // P8: final projection
    if (bid < NGROUP) dev_final(bid, bf, sx, Wp, bp, cnt, out, (float*)smem);
}

// ================= fallback kernels (non-cooperative path) =================
__global__ __launch_bounds__(256) void fk_setup(const void* x, const int* ei,
                                                const void* W1, const void* W2,
                                                __hip_bfloat16* Wt1, __hip_bfloat16* Wt2,
                                                int* H, float* sx, int* cnt) {
    __shared__ int smem[HALFN];
    int bid = blockIdx.x, t = threadIdx.x;
    if (bid < NBLK) {
        int f = probe_edge64(ei);
        dev_hist(bid, f, ei, H, smem);
    } else {
        int bf = probe_xbf((const unsigned int*)x);
        dev_wt(bid - NBLK, bf, W1, W2, Wt1, Wt2);
        if (bid == NBLK) {
            for (int q = t; q < NGROUP * HC; q += 256) sx[q] = 0.f;
            if (t < NGROUP) cnt[t] = 0;
        }
    }
}
__global__ __launch_bounds__(256) void fk_colsum(const int* H, int* deg, int* bsum) {
    __shared__ int wred[4];
    dev_colsum(blockIdx.x, H, deg, bsum, wred);
}
__global__ __launch_bounds__(256) void fk_base(int* H, const int* deg, const int* bsum,
                                               int* off, int* csr) {
    __shared__ int scr[5];
    dev_base(blockIdx.x, H, deg, bsum, off, csr, scr);
}
__global__ __launch_bounds__(256) void fk_scatter(const int* ei, const int* H, int* csr) {
    __shared__ int smem[HALFN];
    int f = probe_edge64(ei);
    dev_scatter(blockIdx.x, f, ei, H, csr, smem);
}
__global__ __launch_bounds__(256) void fk_gemm(const void* x, const void* A,
                                               const __hip_bfloat16* Bt, __hip_bfloat16* Hout,
                                               const void* a_src, const void* a_dst,
                                               float* es4, float* ed4, float* gpart, int force_bf) {
    __shared__ u32x4 hst4[512];
    int bf = probe_xbf((const unsigned int*)x);
    dev_gemm(blockIdx.x, A, Bt, Hout, a_src, a_dst, es4, ed4, gpart, bf, force_bf | bf, hst4);
}
__global__ __launch_bounds__(256) void fk_agg(const void* x, const __hip_bfloat16* Hb,
                                              const float* es4, const float* ed4,
                                              const void* bias, const int* off, const int* csr,
                                              const float* gpart, __hip_bfloat16* out) {
    __shared__ int smem[1284];
    int bf = probe_xbf((const unsigned int*)x);
    dev_agg(blockIdx.x * 4 + (threadIdx.x >> 6), MB * 4, Hb, es4, ed4, bias, off, csr,
            gpart, bf, out, smem);
}
__global__ __launch_bounds__(256) void fk_groupsum(const int* ei, const __hip_bfloat16* X2,
                                                   const int* batch, float* sx, int* cnt) {
    int f = probe_edge64(ei);
    dev_groupsum(blockIdx.x, f, X2, batch, sx, cnt);
}
__global__ __launch_bounds__(256) void fk_final(const void* x, const float* sx,
                                                const void* Wp, const void* bp,
                                                const int* cnt, void* out) {
    __shared__ float red[256];
    int bf = probe_xbf((const unsigned int*)x);
    dev_final(blockIdx.x, bf, sx, Wp, bp, cnt, out, red);
}

extern "C" void kernel_launch(void* const* d_in, const int* in_sizes, int n_in,
                              void* d_out, int out_size, void* d_ws, size_t ws_size,
                              hipStream_t stream) {
    (void)in_sizes; (void)n_in; (void)out_size; (void)ws_size;
    const void* x   = d_in[0];
    const int*  ei  = (const int*)d_in[1];
    const int*  bat = (const int*)d_in[2];
    const void* W1  = d_in[3];
    const void* as1 = d_in[4];
    const void* ad1 = d_in[5];
    const void* b1  = d_in[6];
    const void* W2  = d_in[7];
    const void* as2 = d_in[8];
    const void* ad2 = d_in[9];
    const void* b2  = d_in[10];
    const void* Wp  = d_in[11];
    const void* bp  = d_in[12];

    char* ws = (char*)d_ws;
    size_t o = 0;
    auto alloc = [&](size_t bytes) -> char* {
        char* p = ws + o;
        o += (bytes + 255) & ~(size_t)255;
        return p;
    };
    __hip_bfloat16* hb  = (__hip_bfloat16*)alloc((size_t)NNODES * HC * 2);
    __hip_bfloat16* xb  = (__hip_bfloat16*)alloc((size_t)NNODES * HC * 2);
    __hip_bfloat16* xb2 = (__hip_bfloat16*)alloc((size_t)NNODES * HC * 2);
    __hip_bfloat16* Wt1 = (__hip_bfloat16*)alloc((size_t)HC * HC * 2);
    __hip_bfloat16* Wt2 = (__hip_bfloat16*)alloc((size_t)HC * HC * 2);
    float* es = (float*)alloc((size_t)NNODES * 4 * 4);
    float* ed = (float*)alloc((size_t)NNODES * 4 * 4);
    int* H    = (int*)alloc((size_t)NBLK * NNODES * 4);
    int* deg  = (int*)alloc((size_t)NNODES * 4);
    int* off  = (int*)alloc((size_t)(NNODES + 1) * 4);
    int* csr  = (int*)alloc((size_t)ETOT * 4);
    int* bsum = (int*)alloc((size_t)CBLK * 4);
    float* gpart = (float*)alloc((size_t)4 * GPITCH * 4);
    float* sx = (float*)alloc((size_t)NGROUP * HC * 4);
    int* cnt  = (int*)alloc(256);
    void* outp = d_out;

    void* kargs[] = {
        (void*)&x, (void*)&ei, (void*)&bat,
        (void*)&W1, (void*)&as1, (void*)&ad1, (void*)&b1,
        (void*)&W2, (void*)&as2, (void*)&ad2, (void*)&b2,
        (void*)&Wp, (void*)&bp,
        (void*)&hb, (void*)&xb, (void*)&xb2, (void*)&Wt1, (void*)&Wt2,
        (void*)&es, (void*)&ed, (void*)&H, (void*)&deg, (void*)&off, (void*)&csr,
        (void*)&bsum, (void*)&gpart, (void*)&sx, (void*)&cnt, (void*)&outp
    };
    hipError_t err = hipLaunchCooperativeKernel(reinterpret_cast<void*>(k_mega),
                                                dim3(MB), dim3(256), kargs,
                                                (unsigned)SMEMB, stream);
    if (err != hipSuccess) {
        (void)hipGetLastError();  // clear sticky error; run equivalent multi-kernel path
        fk_setup<<<NBLK + 512, 256, 0, stream>>>(x, ei, W1, W2, Wt1, Wt2, H, sx, cnt);
        fk_colsum<<<CBLK, 256, 0, stream>>>(H, deg, bsum);
        fk_base<<<CBLK, 256, 0, stream>>>(H, deg, bsum, off, csr);
        fk_scatter<<<NBLK, 256, 0, stream>>>(ei, H, csr);
        fk_gemm<<<GBLK, 256, 0, stream>>>(x, x, Wt1, hb, as1, ad1, es, ed, gpart, 0);
        fk_agg<<<MB, 256, 0, stream>>>(x, hb, es, ed, b1, off, csr, gpart, xb);
        fk_gemm<<<GBLK, 256, 0, stream>>>(x, xb, Wt2, hb, as2, ad2, es, ed, gpart, 1);
        fk_agg<<<MB, 256, 0, stream>>>(x, hb, es, ed, b2, off, csr, gpart, xb2);
        fk_groupsum<<<250, 256, 0, stream>>>(ei, xb2, bat, sx, cnt);
        fk_final<<<NGROUP, 256, 0, stream>>>(x, sx, Wp, bp, cnt, d_out);
    }
}

// Round 10
// 300.409 us; speedup vs baseline: 3.3822x; 3.3822x over previous
//
#include <hip/hip_runtime.h>
#include <hip/hip_bf16.h>
#include <cstdint>

#define NNODES 20000
#define NEDGES 640000
#define ETOT   (NEDGES + NNODES)
#define NGROUP 64
#define HC     256
#define DOUT   32
#define EBLK   5120                     // edges per CSR-build slice (divides NEDGES)
#define NBLK   (NEDGES / EBLK)          // 125
#define CBLK   ((NNODES + 255) / 256)   // 79
#define GBLK   (NNODES / 16)            // 1250 gemm tiles
#define HALFN  10240                    // scatter pass width (40 KB LDS ints)

typedef short bf16x8 __attribute__((ext_vector_type(8)));
typedef short s16x4  __attribute__((ext_vector_type(4)));
typedef float f32x4  __attribute__((ext_vector_type(4)));
typedef float f32x2  __attribute__((ext_vector_type(2)));
typedef int   s32x4  __attribute__((ext_vector_type(4)));
typedef unsigned int u32x4 __attribute__((ext_vector_type(4)));

__device__ __forceinline__ float bs2f(short v) {
    union { unsigned int u; float f; } c; c.u = ((unsigned int)(unsigned short)v) << 16; return c.f;
}
__device__ __forceinline__ short f2bs(float v) {
    __hip_bfloat16 b = __float2bfloat16(v);
    union { __hip_bfloat16 b; short s; } u; u.b = b; return u.s;
}
__device__ __forceinline__ float ldf(const void* __restrict__ p, size_t i, int bf) {
    return bf ? __bfloat162float(((const __hip_bfloat16*)p)[i]) : ((const float*)p)[i];
}
__device__ __forceinline__ int ld_idx(const int* __restrict__ p, size_t i, int f64) {
    return f64 ? p[2 * i] : p[i];
}
// monotone float<->uint map for atomicMax on floats
__device__ __forceinline__ unsigned enc_f(float f) {
    unsigned u = __float_as_uint(f);
    return (u >> 31) ? ~u : (u | 0x80000000u);
}
__device__ __forceinline__ float dec_f(unsigned e) {
    return (e >> 31) ? __uint_as_float(e & 0x7FFFFFFFu) : __uint_as_float(~e);
}
// local flag probes (every block computes identical values -> no flag round-trip)
__device__ __forceinline__ int probe_edge64(const int* __restrict__ ei) {
    int l = threadIdx.x & 63;
    int zeros = 0;
#pragma unroll
    for (int r = 0; r < 4; r++)
        zeros += __popcll(__ballot(ei[2 * (r * 64 + l) + 1] == 0));
    return (zeros > 200) ? 1 : 0;
}
__device__ __forceinline__ int probe_xbf(const unsigned int* __restrict__ xw) {
    int l = threadIdx.x & 63;
    int ones = 0;
#pragma unroll
    for (int r = 0; r < 4; r++)
        ones += __popcll(__ballot((xw[r * 64 + l] >> 14) & 1));
    return (ones < 64) ? 1 : 0;
}

// ================= setup: hist slices + weight transposes + cnt + inits =================
// Blocks [0,NBLK): single-pass 80KB LDS histogram of EBLK real edges (self-loops
// excluded; k_base adds them). Blocks [NBLK,NBLK+512): Wt transposes. Block NBLK
// additionally zeroes sx, computes per-group node counts, inits gp2 to enc(-inf).
__global__ __launch_bounds__(256) void k_setup(const unsigned int* __restrict__ xw,
                                               const int* __restrict__ ei,
                                               const int* __restrict__ bat,
                                               const void* __restrict__ W1, const void* __restrict__ W2,
                                               __hip_bfloat16* __restrict__ Wt1,
                                               __hip_bfloat16* __restrict__ Wt2,
                                               int* __restrict__ H,
                                               float* __restrict__ sx, int* __restrict__ cnt,
                                               unsigned* __restrict__ gp2) {
    __shared__ int hl[NNODES];  // 80 KB
    int t = threadIdx.x, b = blockIdx.x;
    if (b < NBLK) {
        int f = probe_edge64(ei);
        s32x4* hl4 = reinterpret_cast<s32x4*>(hl);
        for (int i = t; i < NNODES / 4; i += 256) hl4[i] = (s32x4){0, 0, 0, 0};
        __syncthreads();
        int s0 = b * EBLK;
        if (f) {
            const int* d64 = ei + 2 * NEDGES;   // low words at d64[2*i]
            for (int i0 = s0; i0 < s0 + EBLK; i0 += 512) {
                int i = i0 + 2 * t;
                s32x4 v = *reinterpret_cast<const s32x4*>(d64 + 2 * (size_t)i);
                atomicAdd(&hl[v[0]], 1);
                atomicAdd(&hl[v[2]], 1);
            }
        } else {
            const int* d32 = ei + NEDGES;
            for (int i0 = s0; i0 < s0 + EBLK; i0 += 1024) {
                int i = i0 + 4 * t;
                s32x4 v = *reinterpret_cast<const s32x4*>(d32 + i);
                atomicAdd(&hl[v[0]], 1); atomicAdd(&hl[v[1]], 1);
                atomicAdd(&hl[v[2]], 1); atomicAdd(&hl[v[3]], 1);
            }
        }
        __syncthreads();
        s32x4* Hb4 = reinterpret_cast<s32x4*>(H + (size_t)b * NNODES);
        for (int i = t; i < NNODES / 4; i += 256) Hb4[i] = hl4[i];
    } else {
        int bf = probe_xbf(xw);
        int i = (b - NBLK) * 256 + t;  // 131072
        int which = i >> 16;
        int j = i & 65535;
        int k = j >> 8, n = j & 255;
        const void* W = which ? W2 : W1;
        __hip_bfloat16* Wt = which ? Wt2 : Wt1;
        Wt[(size_t)n * 256 + k] = __float2bfloat16(ldf(W, (size_t)k * 256 + n, bf));
        if (b == NBLK) {
            for (int q = t; q < NGROUP * HC; q += 256) sx[q] = 0.f;
            if (t < 256) gp2[t] = 0x007FFFFFu;   // enc(-inf), 4 heads x 64 slots
            // per-group node counts via LDS histogram (batch is sorted; order free)
            int f = probe_edge64(ei);
            if (t < NGROUP) hl[t] = 0;
            __syncthreads();
            for (int r = t; r < NNODES; r += 256) atomicAdd(&hl[ld_idx(bat, r, f)], 1);
            __syncthreads();
            if (t < NGROUP) cnt[t] = hl[t];
        }
    }
}

// deg[n] = 1 (self-loop) + sum_b H[b][n]; per-block totals for k_base's tiny scan.
__global__ __launch_bounds__(256) void k_colsum(const int* __restrict__ H,
                                                int* __restrict__ deg,
                                                int* __restrict__ bsum) {
    __shared__ int wred[4];
    int t = threadIdx.x, n = blockIdx.x * 256 + t;
    int s = 0;
    if (n < NNODES) {
#pragma unroll 5
        for (int b = 0; b < NBLK; b++) s += H[(size_t)b * NNODES + n];
        s += 1;  // self-loop
        deg[n] = s;
    }
    int r = s;
#pragma unroll
    for (int o = 1; o < 64; o <<= 1) r += __shfl_xor(r, o);
    if ((t & 63) == 0) wred[t >> 6] = r;
    __syncthreads();
    if (t == 0) bsum[blockIdx.x] = wred[0] + wred[1] + wred[2] + wred[3];
}

// Per 256-node block: boff = scan of bsum (wave 0), intra-block scan deg -> off[n],
// self-loop csr entry at off[n], then per-block H bases (prefix over NBLK, +1).
__global__ __launch_bounds__(256) void k_base(int* __restrict__ H,
                                              const int* __restrict__ deg,
                                              const int* __restrict__ bsum,
                                              int* __restrict__ off,
                                              int* __restrict__ csr) {
    __shared__ int wtot[4];
    __shared__ int boff_s;
    int t = threadIdx.x, blk = blockIdx.x;
    int n = blk * 256 + t;
    int d = (n < NNODES) ? deg[n] : 0;
    int lane = t & 63, w = t >> 6;
    int sc = d;
#pragma unroll
    for (int o = 1; o < 64; o <<= 1) {
        int u = __shfl_up(sc, o);
        if (lane >= o) sc += u;
    }
    if (lane == 63) wtot[w] = sc;
    if (w == 0) {  // exclusive prefix of block sums (CBLK=79 <= 128)
        int v = (lane < blk) ? bsum[lane] : 0;
        if (lane + 64 < blk) v += bsum[lane + 64];
#pragma unroll
        for (int o = 1; o < 64; o <<= 1) v += __shfl_xor(v, o);
        if (lane == 0) boff_s = v;
    }
    __syncthreads();
    int woff = 0;
    for (int i = 0; i < w; i++) woff += wtot[i];
    int excl = woff + sc - d;
    if (blk == 0 && t == 0) off[NNODES] = ETOT;
    if (n < NNODES) {
        int o0 = boff_s + excl;
        off[n] = o0;
        csr[o0] = n;          // self-loop first
        int run = o0 + 1;
#pragma unroll 5
        for (int b = 0; b < NBLK; b++) {
            size_t idx = (size_t)b * NNODES + n;
            int tt = H[idx];
            H[idx] = run;
            run += tt;
        }
    }
}

// 2-pass scatter body (40 KB LDS window) — used inside the merged k_sg1.
__device__ __forceinline__ void dev_scatter(int b, int f, const int* __restrict__ ei,
                                            const int* __restrict__ H, int* __restrict__ csr,
                                            int* hl) {
    int t = threadIdx.x;
    for (int pass = 0; pass < 2; ++pass) {
        int nbase = pass * HALFN;
        int span = NNODES - nbase; if (span > HALFN) span = HALFN;
        const int* Hb = H + (size_t)b * NNODES + nbase;
        for (int i = t; i < span; i += 256) hl[i] = Hb[i];
        __syncthreads();
        int s0 = b * EBLK;
        if (f) {
            const int* d64 = ei + 2 * NEDGES;
            for (int i0 = s0; i0 < s0 + EBLK; i0 += 512) {
                int i = i0 + 2 * t;
                s32x4 sv = *reinterpret_cast<const s32x4*>(ei + 2 * (size_t)i);
                s32x4 dv = *reinterpret_cast<const s32x4*>(d64 + 2 * (size_t)i);
                unsigned d0 = (unsigned)(dv[0] - nbase), d1 = (unsigned)(dv[2] - nbase);
                if (d0 < (unsigned)span) { int p = atomicAdd(&hl[d0], 1); csr[p] = sv[0]; }
                if (d1 < (unsigned)span) { int p = atomicAdd(&hl[d1], 1); csr[p] = sv[2]; }
            }
        } else {
            const int* d32 = ei + NEDGES;
            for (int i0 = s0; i0 < s0 + EBLK; i0 += 1024) {
                int i = i0 + 4 * t;
                s32x4 sv = *reinterpret_cast<const s32x4*>(ei + i);
                s32x4 dv = *reinterpret_cast<const s32x4*>(d32 + i);
#pragma unroll
                for (int k = 0; k < 4; k++) {
                    unsigned d = (unsigned)(dv[k] - nbase);
                    if (d < (unsigned)span) { int p = atomicAdd(&hl[d], 1); csr[p] = sv[k]; }
                }
            }
        }
        if (pass == 0) __syncthreads();
    }
}

// one 16-row GEMM tile (4 waves; wave w = head w's 64 cols); fused es/ed scores;
// per-head max -> scattered atomicMax tree gp2[w*64 + tile&63] (~20-way/slot).
__device__ __forceinline__ void dev_gemm(int tile, const void* __restrict__ A,
                                         const __hip_bfloat16* __restrict__ Bt,
                                         __hip_bfloat16* __restrict__ Hout,
                                         const void* __restrict__ a_src, const void* __restrict__ a_dst,
                                         float* __restrict__ es4, float* __restrict__ ed4,
                                         unsigned* __restrict__ gp2, int bf, int abf,
                                         u32x4* hst4) {
    int w    = threadIdx.x >> 6;
    int lane = threadIdx.x & 63;
    int mr   = lane & 15;
    int quad = lane >> 4;
    int r0   = tile * 16;
    f32x4 acc[4];
#pragma unroll
    for (int j = 0; j < 4; j++) acc[j] = (f32x4){0.f, 0.f, 0.f, 0.f};
    size_t rowoff = (size_t)(r0 + mr) * HC;
    const __hip_bfloat16* Btw = Bt + (size_t)w * 64 * HC;
    for (int kk = 0; kk < HC; kk += 32) {
        bf16x8 a;
        if (abf) {
            a = *reinterpret_cast<const bf16x8*>((const __hip_bfloat16*)A + rowoff + kk + quad * 8);
        } else {
            const float* af = (const float*)A + rowoff + kk + quad * 8;
            f32x4 lo = *reinterpret_cast<const f32x4*>(af);
            f32x4 hi = *reinterpret_cast<const f32x4*>(af + 4);
#pragma unroll
            for (int ii = 0; ii < 4; ii++) { a[ii] = f2bs(lo[ii]); a[ii + 4] = f2bs(hi[ii]); }
        }
#pragma unroll
        for (int j = 0; j < 4; j++) {
            bf16x8 b = *reinterpret_cast<const bf16x8*>(Btw + (size_t)(j * 16 + mr) * HC + kk + quad * 8);
            acc[j] = __builtin_amdgcn_mfma_f32_16x16x32_bf16(a, b, acc[j], 0, 0, 0);
        }
    }
    short* hst = reinterpret_cast<short*>(hst4);
#pragma unroll
    for (int j = 0; j < 4; j++)
#pragma unroll
        for (int r = 0; r < 4; r++)
            hst[(quad * 4 + r) * HC + w * 64 + j * 16 + mr] = f2bs(acc[j][r]);
    float ps[4] = {0.f, 0.f, 0.f, 0.f}, pd[4] = {0.f, 0.f, 0.f, 0.f};
#pragma unroll
    for (int j = 0; j < 4; j++) {
        float asv = ldf(a_src, (size_t)(w * 64 + j * 16 + mr), bf);
        float adv = ldf(a_dst, (size_t)(w * 64 + j * 16 + mr), bf);
#pragma unroll
        for (int r = 0; r < 4; r++) {
            ps[r] = fmaf(acc[j][r], asv, ps[r]);
            pd[r] = fmaf(acc[j][r], adv, pd[r]);
        }
    }
#pragma unroll
    for (int o = 1; o < 16; o <<= 1)
#pragma unroll
        for (int r = 0; r < 4; r++) {
            ps[r] += __shfl_xor(ps[r], o);
            pd[r] += __shfl_xor(pd[r], o);
        }
    float pm = fmaxf(fmaxf(ps[0], ps[1]), fmaxf(ps[2], ps[3]));
    pm = fmaxf(pm, __shfl_xor(pm, 16));
    pm = fmaxf(pm, __shfl_xor(pm, 32));
    if (lane == 0) atomicMax(&gp2[w * 64 + (tile & 63)], enc_f(pm));
    if (mr == 0)
#pragma unroll
        for (int r = 0; r < 4; r++) {
            int row = r0 + quad * 4 + r;
            es4[(size_t)row * 4 + w] = ps[r];
            ed4[(size_t)row * 4 + w] = pd[r];
        }
    __syncthreads();
    u32x4* dst = reinterpret_cast<u32x4*>((short*)Hout + (size_t)r0 * HC);
    dst[threadIdx.x]       = hst4[threadIdx.x];
    dst[threadIdx.x + 256] = hst4[threadIdx.x + 256];
}

// ================= merged scatter || gemm layer-1 =================
__global__ __launch_bounds__(256) void k_sg1(const void* __restrict__ x,
                                             const int* __restrict__ ei,
                                             const int* __restrict__ H, int* __restrict__ csr,
                                             const __hip_bfloat16* __restrict__ Wt1,
                                             __hip_bfloat16* __restrict__ hb,
                                             const void* __restrict__ as1, const void* __restrict__ ad1,
                                             float* __restrict__ es, float* __restrict__ ed,
                                             unsigned* __restrict__ gp2) {
    __shared__ int smem[HALFN];  // 40 KB (scatter window; gemm uses first 8 KB)
    int b = blockIdx.x;
    if (b < NBLK) {
        int f = probe_edge64(ei);
        dev_scatter(b, f, ei, H, csr, smem);
    } else {
        int bf = probe_xbf((const unsigned int*)x);
        dev_gemm(b - NBLK, x, Wt1, hb, as1, ad1, es, ed, gp2, bf, bf, (u32x4*)smem);
    }
}

__global__ __launch_bounds__(256) void k_gemm2(const void* __restrict__ x,
                                               const __hip_bfloat16* __restrict__ xb,
                                               const __hip_bfloat16* __restrict__ Wt2,
                                               __hip_bfloat16* __restrict__ hb,
                                               const void* __restrict__ as2, const void* __restrict__ ad2,
                                               float* __restrict__ es, float* __restrict__ ed,
                                               unsigned* __restrict__ gp2) {
    __shared__ u32x4 hst4[512];  // 8 KB
    int bf = probe_xbf((const unsigned int*)x);
    dev_gemm(blockIdx.x, xb, Wt2, hb, as2, ad2, es, ed, gp2, bf, 1, hst4);
}

// ================= fused bound-max softmax + aggregation =================
// Prologue: wave wv reduces head wv's 64 gp2 slots (one coalesced 256B read).
// M[h] = leaky(gmax[h] + ed[n][h]) >= all edge scores; pv = exp(ev-M) direct;
// dsum lane-local, one reduce per node. Gather: 16B/lane, half-waves take 8
// consecutive edges, indices/weights via ds_read_b128, packed f32x2 FMA.
__global__ __launch_bounds__(256) void k_agg(const void* __restrict__ x,
                                             const __hip_bfloat16* __restrict__ Hb,
                                             const float* __restrict__ es4, const float* __restrict__ ed4,
                                             const void* __restrict__ bias,
                                             const int* __restrict__ off, const int* __restrict__ csr,
                                             const unsigned* __restrict__ gp2,
                                             __hip_bfloat16* __restrict__ out) {
    __shared__ float p_lds[4][4][64];
    __shared__ int   s_lds[4][64];
    __shared__ float gm_s[4];
    int wv = threadIdx.x >> 6;
    int l  = threadIdx.x & 63;
    int half = l >> 5;
    int hl   = l & 31;
    int hd8  = hl >> 3;
    int bf = probe_xbf((const unsigned int*)x);
    {   // cheap gmax: 64 lanes read head wv's 64 slots
        float m = dec_f(gp2[wv * 64 + l]);
#pragma unroll
        for (int o = 32; o; o >>= 1) m = fmaxf(m, __shfl_xor(m, o));
        if (l == 0) gm_s[wv] = m;
    }
    __syncthreads();
    f32x4 gm = (f32x4){gm_s[0], gm_s[1], gm_s[2], gm_s[3]};
    int n0 = blockIdx.x * 4 + wv;
    for (int n = n0; n < NNODES; n += 10000) {
        int base = off[n], deg = off[n + 1] - base;
        f32x4 edv = *reinterpret_cast<const f32x4*>(ed4 + (size_t)n * 4);
        f32x4 M;
#pragma unroll
        for (int h = 0; h < 4; h++) {
            float t0 = gm[h] + edv[h];
            M[h] = (t0 > 0.f) ? t0 : 0.2f * t0;
        }
        f32x4 dsum = (f32x4){0.f, 0.f, 0.f, 0.f};
        f32x2 acc2[4];
#pragma unroll
        for (int d = 0; d < 4; d++) acc2[d] = (f32x2){0.f, 0.f};
        for (int c0 = 0; c0 < deg; c0 += 64) {
            int cn = min(deg - c0, 64);
            int s = 0;
            f32x4 pv = (f32x4){0.f, 0.f, 0.f, 0.f};
            if (l < cn) {
                s = csr[base + c0 + l];
                f32x4 e = *reinterpret_cast<const f32x4*>(es4 + (size_t)s * 4);
#pragma unroll
                for (int h = 0; h < 4; h++) {
                    float t = e[h] + edv[h];
                    t = (t > 0.f) ? t : 0.2f * t;
                    pv[h] = __expf(t - M[h]);
                }
            }
            s_lds[wv][l] = s;
#pragma unroll
            for (int h = 0; h < 4; h++) p_lds[wv][h][l] = pv[h];
#pragma unroll
            for (int h = 0; h < 4; h++) dsum[h] += pv[h];
            int jn = (cn + 15) & ~15;
            for (int j = 0; j < jn; j += 16) {
                int e0 = j + 8 * half;
                s32x4 sA = *reinterpret_cast<const s32x4*>(&s_lds[wv][e0]);
                s32x4 sB = *reinterpret_cast<const s32x4*>(&s_lds[wv][e0 + 4]);
                f32x4 pA = *reinterpret_cast<const f32x4*>(&p_lds[wv][hd8][e0]);
                f32x4 pB = *reinterpret_cast<const f32x4*>(&p_lds[wv][hd8][e0 + 4]);
                u32x4 hv[8];
#pragma unroll
                for (int i = 0; i < 8; i++) {
                    int sj = (i < 4) ? sA[i & 3] : sB[i & 3];
                    hv[i] = *reinterpret_cast<const u32x4*>(Hb + (size_t)sj * HC + hl * 8);
                }
#pragma unroll
                for (int i = 0; i < 8; i++) {
                    float p = (i < 4) ? pA[i & 3] : pB[i & 3];
#pragma unroll
                    for (int d = 0; d < 4; d++) {
                        unsigned int u = hv[i][d];
                        f32x2 h2;
                        h2.x = __uint_as_float(u << 16);
                        h2.y = __uint_as_float(u & 0xFFFF0000u);
                        acc2[d] += h2 * p;
                    }
                }
            }
        }
#pragma unroll
        for (int o = 32; o; o >>= 1)
#pragma unroll
            for (int h = 0; h < 4; h++) dsum[h] += __shfl_xor(dsum[h], o);
#pragma unroll
        for (int d = 0; d < 4; d++) {
            acc2[d].x += __shfl_xor(acc2[d].x, 32);
            acc2[d].y += __shfl_xor(acc2[d].y, 32);
        }
        float rinv = 1.0f / fmaxf(dsum[hd8], 1e-16f);
        if (half == 0) {
            bf16x8 ov;
#pragma unroll
            for (int d = 0; d < 4; d++) {
                float v0 = acc2[d].x * rinv + ldf(bias, (size_t)hl * 8 + 2 * d, bf);
                float v1 = acc2[d].y * rinv + ldf(bias, (size_t)hl * 8 + 2 * d + 1, bf);
                ov[2 * d]     = f2bs(fmaxf(v0, 0.f));
                ov[2 * d + 1] = f2bs(fmaxf(v1, 0.f));
            }
            *reinterpret_cast<bf16x8*>(out + (size_t)n * HC + hl * 8) = ov;
        }
    }
}

// ---------------- readout: 4-row-parallel boundary-flush group sums ----------------
__global__ __launch_bounds__(256) void k_groupsum(const int* __restrict__ ei,
                                                  const __hip_bfloat16* __restrict__ X2,
                                                  const int* __restrict__ batch,
                                                  float* __restrict__ sx) {
    const int RPB = NNODES / 250;  // 80
    int b = blockIdx.x;
    int f = probe_edge64(ei);
    int sub = threadIdx.x >> 6, l = threadIdx.x & 63;
    int r = b * RPB + sub;
    f32x4 acc = (f32x4){0.f, 0.f, 0.f, 0.f};
    int curg = ld_idx(batch, r, f);
    for (int k = 0; k < RPB / 4; k++, r += 4) {
        int g = ld_idx(batch, r, f);
        if (g != curg) {
#pragma unroll
            for (int c = 0; c < 4; c++) atomicAdd(&sx[(size_t)curg * HC + l * 4 + c], acc[c]);
            acc = (f32x4){0.f, 0.f, 0.f, 0.f}; curg = g;
        }
        s16x4 hv = *reinterpret_cast<const s16x4*>(X2 + (size_t)r * HC + l * 4);
#pragma unroll
        for (int c = 0; c < 4; c++) acc[c] += bs2f(hv[c]);
    }
#pragma unroll
    for (int c = 0; c < 4; c++) atomicAdd(&sx[(size_t)curg * HC + l * 4 + c], acc[c]);
}

// ---------------- final projection: one block per group ----------------
__global__ __launch_bounds__(256) void k_final(const void* __restrict__ x,
                                               const float* __restrict__ sx,
                                               const void* __restrict__ Wp,
                                               const void* __restrict__ bp,
                                               const int* __restrict__ cnt,
                                               void* __restrict__ out) {
    __shared__ float red[8][32];
    int g = blockIdx.x, t = threadIdx.x;
    int c = t & 31, seg = t >> 5;
    int bf = probe_xbf((const unsigned int*)x);
    const float* sxg = sx + (size_t)g * HC;
    float a = 0.f;
#pragma unroll
    for (int k = 0; k < 32; k++) {
        int kk = seg * 32 + k;
        a = fmaf(sxg[kk], ldf(Wp, (size_t)kk * DOUT + c, bf), a);
    }
    red[seg][c] = a;
    __syncthreads();
    if (t < 32) {
        float s = 0.f;
#pragma unroll
        for (int i = 0; i < 8; i++) s += red[i][t];
        int ct = cnt[g];
        float v = (ct > 0) ? (s / ct + ldf(bp, (size_t)t, bf)) : 0.f;
        if (bf) ((__hip_bfloat16*)out)[g * DOUT + t] = __float2bfloat16(v);
        else    ((float*)out)[g * DOUT + t]          = v;
    }
}

extern "C" void kernel_launch(void* const* d_in, const int* in_sizes, int n_in,
                              void* d_out, int out_size, void* d_ws, size_t ws_size,
                              hipStream_t stream) {
    (void)in_sizes; (void)n_in; (void)out_size; (void)ws_size;
    const void* x   = d_in[0];
    const int*  ei  = (const int*)d_in[1];
    const int*  bat = (const int*)d_in[2];
    const void* W1  = d_in[3];
    const void* as1 = d_in[4];
    const void* ad1 = d_in[5];
    const void* b1  = d_in[6];
    const void* W2  = d_in[7];
    const void* as2 = d_in[8];
    const void* ad2 = d_in[9];
    const void* b2  = d_in[10];
    const void* Wp  = d_in[11];
    const void* bp  = d_in[12];

    char* ws = (char*)d_ws;
    size_t o = 0;
    auto alloc = [&](size_t bytes) -> char* {
        char* p = ws + o;
        o += (bytes + 255) & ~(size_t)255;
        return p;
    };
    __hip_bfloat16* hb  = (__hip_bfloat16*)alloc((size_t)NNODES * HC * 2);
    __hip_bfloat16* xb  = (__hip_bfloat16*)alloc((size_t)NNODES * HC * 2);
    __hip_bfloat16* xb2 = (__hip_bfloat16*)alloc((size_t)NNODES * HC * 2);
    __hip_bfloat16* Wt1 = (__hip_bfloat16*)alloc((size_t)HC * HC * 2);
    __hip_bfloat16* Wt2 = (__hip_bfloat16*)alloc((size_t)HC * HC * 2);
    float* es = (float*)alloc((size_t)NNODES * 4 * 4);
    float* ed = (float*)alloc((size_t)NNODES * 4 * 4);
    int* H    = (int*)alloc((size_t)NBLK * NNODES * 4);
    int* deg  = (int*)alloc((size_t)NNODES * 4);
    int* off  = (int*)alloc((size_t)(NNODES + 1) * 4);
    int* csr  = (int*)alloc((size_t)ETOT * 4);
    int* bsum = (int*)alloc((size_t)CBLK * 4);
    unsigned* gp2 = (unsigned*)alloc(256 * 4);   // 4 heads x 64 atomicMax slots
    float* sx = (float*)alloc((size_t)NGROUP * HC * 4);
    int* cnt  = (int*)alloc(256);

    // 9 launches, no grid.sync
    k_setup<<<NBLK + 512, 256, 0, stream>>>((const unsigned int*)x, ei, bat, W1, W2,
                                            Wt1, Wt2, H, sx, cnt, gp2);
    k_colsum<<<CBLK, 256, 0, stream>>>(H, deg, bsum);
    k_base<<<CBLK, 256, 0, stream>>>(H, deg, bsum, off, csr);
    k_sg1<<<NBLK + GBLK, 256, 0, stream>>>(x, ei, H, csr, Wt1, hb, as1, ad1, es, ed, gp2);
    k_agg<<<2500, 256, 0, stream>>>(x, hb, es, ed, b1, off, csr, gp2, xb);
    k_gemm2<<<GBLK, 256, 0, stream>>>(x, xb, Wt2, hb, as2, ad2, es, ed, gp2);
    k_agg<<<2500, 256, 0, stream>>>(x, hb, es, ed, b2, off, csr, gp2, xb2);
    k_groupsum<<<250, 256, 0, stream>>>(ei, xb2, bat, sx);
    k_final<<<NGROUP, 256, 0, stream>>>(x, sx, Wp, bp, cnt, d_out);
}